// Round 7
// baseline (459.369 us; speedup 1.0000x reference)
//
#include <hip/hip_runtime.h>
#include <stdint.h>

typedef __attribute__((ext_vector_type(4))) float f32x4;
typedef __attribute__((ext_vector_type(8))) _Float16 h8;
typedef __attribute__((ext_vector_type(4))) float f4v;
typedef __attribute__((ext_vector_type(4))) _Float16 h4v;

#define B_ 4
#define T_ 2048
#define C_ 1024
#define NH 16
#define HD 64
#define M_ (B_*T_)   // 8192
#define KD 1024      // reduction dim of all GEMMs

#define MFMA16(a, b, c) __builtin_amdgcn_mfma_f32_16x16x32_f16(a, b, c, 0, 0, 0)

#if __has_builtin(__builtin_amdgcn_exp2f)
#define EXP2(x) __builtin_amdgcn_exp2f(x)
#else
#define EXP2(x) exp2f(x)
#endif

#if __has_builtin(__builtin_amdgcn_cvt_pkrtz)
static __device__ __forceinline__ unsigned pk16(float a, float b) {
  return __builtin_bit_cast(unsigned, __builtin_amdgcn_cvt_pkrtz(a, b));
}
#else
static __device__ __forceinline__ unsigned pk16(float a, float b) {
  union { _Float16 h[2]; unsigned u; } x;
  x.h[0] = (_Float16)a; x.h[1] = (_Float16)b; return x.u;
}
#endif

// async global->LDS, 16B per lane; LDS dest must be wave-uniform base (HW adds lane*16)
#define GL2LDS16(g, l) \
  __builtin_amdgcn_global_load_lds((const __attribute__((address_space(1))) unsigned int*)(g), \
      (__attribute__((address_space(3))) unsigned int*)(unsigned int)(uintptr_t)(l), 16, 0, 0)

__global__ void cast_x_kernel(const float* __restrict__ src, _Float16* __restrict__ dst, int n4) {
  int i = blockIdx.x * blockDim.x + threadIdx.x;
  if (i < n4) {
    f4v v = ((const f4v*)src)[i];
    ((h4v*)dst)[i] = __builtin_convertvector(v, h4v);
  }
}

// Stage a 128x32 fp32 tile (rows stride KD) into fp16 LDS [128][32], row-major.
__device__ __forceinline__ void stage_f32_128x32(const float* src, _Float16* dst, int lane, int wav) {
  #pragma unroll
  for (int hh = 0; hh < 2; hh++) {
    int row = hh*64 + wav*16 + (lane >> 2);
    int colf = (lane & 3) * 8;
    const float* p = src + (size_t)row * KD + colf;
    f4v a = *(const f4v*)p;
    f4v b = *(const f4v*)(p + 4);
    h8 v;
    v[0]=(_Float16)a[0]; v[1]=(_Float16)a[1]; v[2]=(_Float16)a[2]; v[3]=(_Float16)a[3];
    v[4]=(_Float16)b[0]; v[5]=(_Float16)b[1]; v[6]=(_Float16)b[2]; v[7]=(_Float16)b[3];
    *(h8*)(dst + row*32 + colf) = v;
  }
}

// ---------------- QKV GEMM: Out[M][N] = A[M][K] * W[N][K]^T + bias, 128x128 tile, BK=32 ----------------
// sel==2 (V) is written TRANSPOSED as Vt[b][h][d][t] so attention needs no LDS transpose.
template<int AMODE>
__global__ __launch_bounds__(256) void gemm_qkv_kernel(
    const _Float16* __restrict__ Xh, const float* __restrict__ Xf,
    const float* __restrict__ Wq, const float* __restrict__ Wk, const float* __restrict__ Wv,
    const float* __restrict__ bq, const float* __restrict__ bk, const float* __restrict__ bv,
    _Float16* __restrict__ Qo, _Float16* __restrict__ Ko, _Float16* __restrict__ Vo)
{
  __shared__ _Float16 As[128*32];
  __shared__ _Float16 Bs[128*32];
  int tid = threadIdx.x;
  int lane = tid & 63, wav = tid >> 6;
  int mb = blockIdx.x;
  int nbg = blockIdx.y;
  int sel = nbg >> 3, nb = nbg & 7;
  const float* W = sel == 0 ? Wq : (sel == 1 ? Wk : Wv);
  const float* bias = sel == 0 ? bq : (sel == 1 ? bk : bv);
  _Float16* Out = sel == 0 ? Qo : (sel == 1 ? Ko : Vo);
  int m0 = mb * 128, n0 = nb * 128;

  f32x4 acc[4][4] = {};

  int r_in = lane >> 2;          // 0..15 row within 16-row chunk
  int c8   = (lane & 3) * 8;     // k-element offset 0,8,16,24
  int l15 = lane & 15, l4 = lane >> 4;
  int wr = (wav >> 1) * 64, wc = (wav & 1) * 64;

  for (int k0 = 0; k0 < KD; k0 += 32) {
    if (AMODE == 0) {
      GL2LDS16(Xh + (size_t)(m0 +      wav*16 + r_in)*KD + k0 + c8, As +        wav*512);
      GL2LDS16(Xh + (size_t)(m0 + 64 + wav*16 + r_in)*KD + k0 + c8, As + 2048 + wav*512);
    } else {
      stage_f32_128x32(Xf + (size_t)m0 * KD + k0, As, lane, wav);
    }
    stage_f32_128x32(W + (size_t)n0 * KD + k0, Bs, lane, wav);
    __syncthreads();

    h8 af[4], bf[4];
    #pragma unroll
    for (int f = 0; f < 4; f++) {
      af[f] = *(const h8*)(As + (wr + f*16 + l15)*32 + l4*8);
      bf[f] = *(const h8*)(Bs + (wc + f*16 + l15)*32 + l4*8);
    }
    #pragma unroll
    for (int i = 0; i < 4; i++)
      #pragma unroll
      for (int j = 0; j < 4; j++)
        acc[i][j] = MFMA16(af[i], bf[j], acc[i][j]);
    __syncthreads();
  }

  if (sel == 2) {
    // transposed V epilogue: Vt[((b*NH+h)*HD+d)*T_ + t], 4 consecutive t per reg quad
    #pragma unroll
    for (int i = 0; i < 4; i++) {
      int mrow = m0 + wr + i*16 + l4*4;
      int bb = mrow >> 11, t = mrow & 2047;
      #pragma unroll
      for (int j = 0; j < 4; j++) {
        int ncol = n0 + wc + j*16 + l15;
        float bval = bias[ncol];
        int hh = ncol >> 6, d = ncol & 63;
        h4v v;
        #pragma unroll
        for (int r = 0; r < 4; r++) v[r] = (_Float16)(acc[i][j][r] + bval);
        *(h4v*)(Vo + ((size_t)(bb*NH + hh)*HD + d)*T_ + t) = v;
      }
    }
  } else {
    #pragma unroll
    for (int i = 0; i < 4; i++) {
      int mrow = m0 + wr + i*16 + l4*4;
      #pragma unroll
      for (int j = 0; j < 4; j++) {
        int ncol = n0 + wc + j*16 + l15;
        float bval = bias[ncol];
        #pragma unroll
        for (int r = 0; r < 4; r++)
          Out[(size_t)(mrow + r)*C_ + ncol] = (_Float16)(acc[i][j][r] + bval);
      }
    }
  }
}

// ---------------- Output projection: Out[M][N] = A[M][K](fp16) * W[N][K]^T(fp32) + bias, clamp ±10 ----------------
__global__ __launch_bounds__(256) void gemm_proj_kernel(
    const _Float16* __restrict__ A, const float* __restrict__ W,
    const float* __restrict__ bias, float* __restrict__ Out)
{
  __shared__ _Float16 As[128*32];
  __shared__ _Float16 Bs[128*32];
  int tid = threadIdx.x;
  int lane = tid & 63, wav = tid >> 6;
  int m0 = blockIdx.x * 128, n0 = blockIdx.y * 128;

  f32x4 acc[4][4] = {};
  int r_in = lane >> 2;
  int c8   = (lane & 3) * 8;
  int l15 = lane & 15, l4 = lane >> 4;
  int wr = (wav >> 1) * 64, wc = (wav & 1) * 64;

  for (int k0 = 0; k0 < KD; k0 += 32) {
    GL2LDS16(A + (size_t)(m0 +      wav*16 + r_in)*KD + k0 + c8, As +        wav*512);
    GL2LDS16(A + (size_t)(m0 + 64 + wav*16 + r_in)*KD + k0 + c8, As + 2048 + wav*512);
    stage_f32_128x32(W + (size_t)n0 * KD + k0, Bs, lane, wav);
    __syncthreads();

    h8 af[4], bf[4];
    #pragma unroll
    for (int f = 0; f < 4; f++) {
      af[f] = *(const h8*)(As + (wr + f*16 + l15)*32 + l4*8);
      bf[f] = *(const h8*)(Bs + (wc + f*16 + l15)*32 + l4*8);
    }
    #pragma unroll
    for (int i = 0; i < 4; i++)
      #pragma unroll
      for (int j = 0; j < 4; j++)
        acc[i][j] = MFMA16(af[i], bf[j], acc[i][j]);
    __syncthreads();
  }

  #pragma unroll
  for (int i = 0; i < 4; i++) {
    int mrow = m0 + wr + i*16 + l4*4;
    #pragma unroll
    for (int j = 0; j < 4; j++) {
      int ncol = n0 + wc + j*16 + l15;
      float bval = bias[ncol];
      #pragma unroll
      for (int r = 0; r < 4; r++) {
        float v = acc[i][j][r] + bval;
        v = fminf(10.f, fmaxf(-10.f, v));
        Out[(size_t)(mrow + r)*C_ + ncol] = v;
      }
    }
  }
}

// ---------------- Flash attention, causal, KV-split, KVBLK=64. ----------------
// Block = 128 threads = 2 waves on ONE 32-row q tile; wave0 takes KV blocks [0,ceil(a/2)),
// wave1 takes [ceil(a/2), a). Each keeps partial (m, l, acc) in the log2 domain;
// wave1 posts partials to LDS, one barrier, wave0 merges (flash-merge: w_i = 2^(m_i-m*))
// and stores. 4096 blocks, longest tile first -> 16 waves/CU resident (VGPR<=128).
// Swapped QK^T (S^T = K*Q^T) keeps q lane-local; Q pre-scaled by (1/8)*log2(e);
// defer-max (THR=8, log2 units); V pre-transposed in global (Vt[b][h][d][t]);
// O overwrites Q in place (each block's rows x head-slice are exclusively its own).
__global__ __launch_bounds__(128, 4) void attn_kernel(
    const _Float16* Q, const _Float16* __restrict__ K,
    const _Float16* __restrict__ Vt, _Float16* O)
{
  __shared__ _Float16 Plds[2][2][16*72];   // [wave][chain] P[16 q][64 k], row stride 72
  __shared__ float MrgAcc[2][16][64];      // [chain][q row][d col] wave1 partial O
  __shared__ float MrgML[2][2][16];        // [chain][{m,l}][q row]
  int lane = threadIdx.x & 63;
  int w = threadIdx.x >> 6;                // 0 or 1
  int p = blockIdx.x;                      // 4096 blocks
  int t = 63 - (p >> 6);                   // tile, longest first
  int bh = p & 63;
  int b = bh >> 4, h = bh & 15;
  int l15 = lane & 15, l4 = lane >> 4;
  _Float16* PlA = &Plds[w][0][0];
  _Float16* PlB = &Plds[w][1][0];
  const _Float16* Kbh = K + (size_t)b*T_*C_ + h*HD;
  const _Float16* Vbh = Vt + (size_t)(b*NH + h)*HD*T_;
  const _Float16 QSC = (_Float16)0.18033688011f;   // (1/8)*log2(e)

  int q0 = t * 32;
  int qa = q0 + l15, qb = q0 + 16 + l15;
  int a  = (t >> 1) + 1;                   // total 64-key blocks for this tile
  int h0 = (a + 1) >> 1;
  int ibs = w ? h0 : 0;
  int ibe = w ? a : h0;
  int lastb = (a - 1) * 64;                // the (only) masked key block

  const _Float16* qp0 = Q + (size_t)(b*T_ + qa)*C_ + h*HD;
  const _Float16* qp1 = Q + (size_t)(b*T_ + qb)*C_ + h*HD;
  h8 qf00 = *(const h8*)(qp0 + l4*8)      * QSC;
  h8 qf01 = *(const h8*)(qp0 + 32 + l4*8) * QSC;
  h8 qf10 = *(const h8*)(qp1 + l4*8)      * QSC;
  h8 qf11 = *(const h8*)(qp1 + 32 + l4*8) * QSC;

  f32x4 accA[4] = {}, accB[4] = {};
  float mA = -INFINITY, lAp = 0.f;
  float mB = -INFINITY, lBp = 0.f;

#define CHAIN(sv, qrow, m, lp, acc, Pl)                                        \
  {                                                                            \
    float sc[16];                                                              \
    _Pragma("unroll") for (int g = 0; g < 4; g++) {                            \
      sc[g*4+0] = sv[g][0]; sc[g*4+1] = sv[g][1];                              \
      sc[g*4+2] = sv[g][2]; sc[g*4+3] = sv[g][3];                              \
    }                                                                          \
    if (kb == lastb) {                                                         \
      _Pragma("unroll") for (int g = 0; g < 4; g++)                            \
        _Pragma("unroll") for (int r = 0; r < 4; r++)                          \
          if (kb + g*16 + l4*4 + r > (qrow)) sc[g*4+r] = -INFINITY;            \
    }                                                                          \
    float mx = sc[0];                                                          \
    _Pragma("unroll") for (int j = 1; j < 16; j++) mx = fmaxf(mx, sc[j]);      \
    mx = fmaxf(mx, __shfl_xor(mx, 16));                                        \
    mx = fmaxf(mx, __shfl_xor(mx, 32));                                        \
    if (__any(mx > (m) + 8.f)) {                                               \
      float mn = fmaxf((m), mx);                                               \
      float al = EXP2((m) - mn);                                               \
      (lp) *= al;                                                              \
      float av0 = __shfl(al, l4*4+0), av1 = __shfl(al, l4*4+1);                \
      float av2 = __shfl(al, l4*4+2), av3 = __shfl(al, l4*4+3);                \
      _Pragma("unroll") for (int c2 = 0; c2 < 4; c2++) {                       \
        acc[c2][0] *= av0; acc[c2][1] *= av1;                                  \
        acc[c2][2] *= av2; acc[c2][3] *= av3;                                  \
      }                                                                        \
      (m) = mn;                                                                \
    }                                                                          \
    _Pragma("unroll") for (int g = 0; g < 4; g++) {                            \
      float e0 = EXP2(sc[g*4+0] - (m)), e1 = EXP2(sc[g*4+1] - (m));            \
      float e2 = EXP2(sc[g*4+2] - (m)), e3 = EXP2(sc[g*4+3] - (m));            \
      (lp) += (e0 + e1) + (e2 + e3);                                           \
      uint2 u; u.x = pk16(e0, e1); u.y = pk16(e2, e3);                         \
      *(uint2*)((Pl) + l15*72 + g*16 + l4*4) = u;                              \
    }                                                                          \
  }

  h8 kf0, kf1, kf2, kf3, kf4, kf5, kf6, kf7;
  {
    const _Float16* k0p = Kbh + (size_t)(ibs * 64) * C_;
    kf0 = *(const h8*)(k0p + (size_t)(     l15)*C_ + l4*8);
    kf1 = *(const h8*)(k0p + (size_t)(     l15)*C_ + 32 + l4*8);
    kf2 = *(const h8*)(k0p + (size_t)(16 + l15)*C_ + l4*8);
    kf3 = *(const h8*)(k0p + (size_t)(16 + l15)*C_ + 32 + l4*8);
    kf4 = *(const h8*)(k0p + (size_t)(32 + l15)*C_ + l4*8);
    kf5 = *(const h8*)(k0p + (size_t)(32 + l15)*C_ + 32 + l4*8);
    kf6 = *(const h8*)(k0p + (size_t)(48 + l15)*C_ + l4*8);
    kf7 = *(const h8*)(k0p + (size_t)(48 + l15)*C_ + 32 + l4*8);
  }

  #pragma unroll 1
  for (int ib = ibs; ib < ibe; ib++) {
    int kb = ib << 6;
    // V^T fragments (consumed at iteration end -> latency hidden under softmax)
    h8 vf00 = *(const h8*)(Vbh + (size_t)(     l15)*T_ + kb + l4*8);
    h8 vf01 = *(const h8*)(Vbh + (size_t)(     l15)*T_ + kb + 32 + l4*8);
    h8 vf10 = *(const h8*)(Vbh + (size_t)(16 + l15)*T_ + kb + l4*8);
    h8 vf11 = *(const h8*)(Vbh + (size_t)(16 + l15)*T_ + kb + 32 + l4*8);
    h8 vf20 = *(const h8*)(Vbh + (size_t)(32 + l15)*T_ + kb + l4*8);
    h8 vf21 = *(const h8*)(Vbh + (size_t)(32 + l15)*T_ + kb + 32 + l4*8);
    h8 vf30 = *(const h8*)(Vbh + (size_t)(48 + l15)*T_ + kb + l4*8);
    h8 vf31 = *(const h8*)(Vbh + (size_t)(48 + l15)*T_ + kb + 32 + l4*8);

    f32x4 z = {};
    f32x4 sA[4], sB[4];
    sA[0] = MFMA16(kf1, qf01, MFMA16(kf0, qf00, z));
    sA[1] = MFMA16(kf3, qf01, MFMA16(kf2, qf00, z));
    sA[2] = MFMA16(kf5, qf01, MFMA16(kf4, qf00, z));
    sA[3] = MFMA16(kf7, qf01, MFMA16(kf6, qf00, z));
    sB[0] = MFMA16(kf1, qf11, MFMA16(kf0, qf10, z));
    sB[1] = MFMA16(kf3, qf11, MFMA16(kf2, qf10, z));
    sB[2] = MFMA16(kf5, qf11, MFMA16(kf4, qf10, z));
    sB[3] = MFMA16(kf7, qf11, MFMA16(kf6, qf10, z));

    if (ib + 1 < ibe) {      // register-prefetch next K tile
      const _Float16* kn = Kbh + (size_t)(kb + 64)*C_;
      kf0 = *(const h8*)(kn + (size_t)(     l15)*C_ + l4*8);
      kf1 = *(const h8*)(kn + (size_t)(     l15)*C_ + 32 + l4*8);
      kf2 = *(const h8*)(kn + (size_t)(16 + l15)*C_ + l4*8);
      kf3 = *(const h8*)(kn + (size_t)(16 + l15)*C_ + 32 + l4*8);
      kf4 = *(const h8*)(kn + (size_t)(32 + l15)*C_ + l4*8);
      kf5 = *(const h8*)(kn + (size_t)(32 + l15)*C_ + 32 + l4*8);
      kf6 = *(const h8*)(kn + (size_t)(48 + l15)*C_ + l4*8);
      kf7 = *(const h8*)(kn + (size_t)(48 + l15)*C_ + 32 + l4*8);
    }

    CHAIN(sA, qa, mA, lAp, accA, PlA)
    CHAIN(sB, qb, mB, lBp, accB, PlB)

    h8 paA0 = *(const h8*)(PlA + l15*72 + l4*8);
    h8 paA1 = *(const h8*)(PlA + l15*72 + 32 + l4*8);
    h8 paB0 = *(const h8*)(PlB + l15*72 + l4*8);
    h8 paB1 = *(const h8*)(PlB + l15*72 + 32 + l4*8);
    accA[0] = MFMA16(paA1, vf01, MFMA16(paA0, vf00, accA[0]));
    accA[1] = MFMA16(paA1, vf11, MFMA16(paA0, vf10, accA[1]));
    accA[2] = MFMA16(paA1, vf21, MFMA16(paA0, vf20, accA[2]));
    accA[3] = MFMA16(paA1, vf31, MFMA16(paA0, vf30, accA[3]));
    accB[0] = MFMA16(paB1, vf01, MFMA16(paB0, vf00, accB[0]));
    accB[1] = MFMA16(paB1, vf11, MFMA16(paB0, vf10, accB[1]));
    accB[2] = MFMA16(paB1, vf21, MFMA16(paB0, vf20, accB[2]));
    accB[3] = MFMA16(paB1, vf31, MFMA16(paB0, vf30, accB[3]));
  }
#undef CHAIN

  // full row-sum reduce of this wave's l partials
  lAp += __shfl_xor(lAp, 16); lAp += __shfl_xor(lAp, 32);
  lBp += __shfl_xor(lBp, 16); lBp += __shfl_xor(lBp, 32);

  if (w == 1) {
    if (l4 == 0) {
      MrgML[0][0][l15] = mA; MrgML[0][1][l15] = lAp;
      MrgML[1][0][l15] = mB; MrgML[1][1][l15] = lBp;
    }
    #pragma unroll
    for (int c2 = 0; c2 < 4; c2++)
      #pragma unroll
      for (int r = 0; r < 4; r++) {
        MrgAcc[0][l4*4 + r][c2*16 + l15] = accA[c2][r];
        MrgAcc[1][l4*4 + r][c2*16 + l15] = accB[c2][r];
      }
  }
  __syncthreads();
  if (w == 0) {
    #pragma unroll
    for (int r = 0; r < 4; r++) {
      int row = l4*4 + r;
      float m0a = __shfl(mA, row), l0a = __shfl(lAp, row);
      float m0b = __shfl(mB, row), l0b = __shfl(lBp, row);
      float m1a = MrgML[0][0][row], l1a = MrgML[0][1][row];
      float m1b = MrgML[1][0][row], l1b = MrgML[1][1][row];
      float msa = fmaxf(m0a, m1a), msb = fmaxf(m0b, m1b);
      float w0a = EXP2(m0a - msa), w1a = EXP2(m1a - msa);
      float w0b = EXP2(m0b - msb), w1b = EXP2(m1b - msb);
      float ra = 1.f / (w0a*l0a + w1a*l1a);
      float rb = 1.f / (w0b*l0b + w1b*l1b);
      float s0a = w0a*ra, s1a = w1a*ra;
      float s0b = w0b*rb, s1b = w1b*rb;
      #pragma unroll
      for (int c2 = 0; c2 < 4; c2++) {
        float va = accA[c2][r]*s0a + MrgAcc[0][row][c2*16 + l15]*s1a;
        float vb = accB[c2][r]*s0b + MrgAcc[1][row][c2*16 + l15]*s1b;
        va = fminf(10.f, fmaxf(-10.f, va));
        vb = fminf(10.f, fmaxf(-10.f, vb));
        O[(size_t)(b*T_ + q0      + row)*C_ + h*HD + c2*16 + l15] = (_Float16)va;
        O[(size_t)(b*T_ + q0 + 16 + row)*C_ + h*HD + c2*16 + l15] = (_Float16)vb;
      }
    }
  }
}

extern "C" void kernel_launch(void* const* d_in, const int* in_sizes, int n_in,
                              void* d_out, int out_size, void* d_ws, size_t ws_size,
                              hipStream_t stream) {
  (void)in_sizes; (void)n_in; (void)out_size;
  const float* x  = (const float*)d_in[0];
  const float* wq = (const float*)d_in[1];
  const float* bq = (const float*)d_in[2];
  const float* wk = (const float*)d_in[3];
  const float* bk = (const float*)d_in[4];
  const float* wv = (const float*)d_in[5];
  const float* bv = (const float*)d_in[6];
  const float* wp = (const float*)d_in[7];
  const float* bp = (const float*)d_in[8];
  float* out = (float*)d_out;

  char* ws = (char*)d_ws;
  const size_t MB = 1ull << 20;
  _Float16* qh = (_Float16*)(ws + 0*MB);    // 16 MB; attention output written in place
  _Float16* kh = (_Float16*)(ws + 16*MB);   // 16 MB
  _Float16* vh = (_Float16*)(ws + 32*MB);   // 16 MB, TRANSPOSED layout [b][h][d][t]
  _Float16* xh = (_Float16*)(ws + 48*MB);   // 16 MB (only if ws_size >= 64 MB)

  bool use_xh = ws_size >= 64*MB;
  if (use_xh) {
    cast_x_kernel<<<dim3((M_*C_/4) / 256), 256, 0, stream>>>(x, xh, M_*C_/4);
    gemm_qkv_kernel<0><<<dim3(M_/128, 24), 256, 0, stream>>>(
        xh, nullptr, wq, wk, wv, bq, bk, bv, qh, kh, vh);
  } else {
    gemm_qkv_kernel<1><<<dim3(M_/128, 24), 256, 0, stream>>>(
        nullptr, x, wq, wk, wv, bq, bk, bv, qh, kh, vh);
  }
  attn_kernel<<<dim3(4096), 128, 0, stream>>>(qh, kh, vh, qh);
  gemm_proj_kernel<<<dim3(M_/128, C_/128), 256, 0, stream>>>(qh, wp, bp, out);
}

// Round 8
// 243.326 us; speedup vs baseline: 1.8879x; 1.8879x over previous
//
#include <hip/hip_runtime.h>
#include <stdint.h>

typedef __attribute__((ext_vector_type(4))) float f32x4;
typedef __attribute__((ext_vector_type(8))) _Float16 h8;
typedef __attribute__((ext_vector_type(4))) float f4v;
typedef __attribute__((ext_vector_type(4))) _Float16 h4v;

#define B_ 4
#define T_ 2048
#define C_ 1024
#define NH 16
#define HD 64
#define M_ (B_*T_)   // 8192
#define KD 1024      // reduction dim of all GEMMs

#define MFMA16(a, b, c) __builtin_amdgcn_mfma_f32_16x16x32_f16(a, b, c, 0, 0, 0)

#if __has_builtin(__builtin_amdgcn_exp2f)
#define EXP2(x) __builtin_amdgcn_exp2f(x)
#else
#define EXP2(x) exp2f(x)
#endif

#if __has_builtin(__builtin_amdgcn_cvt_pkrtz)
static __device__ __forceinline__ unsigned pk16(float a, float b) {
  return __builtin_bit_cast(unsigned, __builtin_amdgcn_cvt_pkrtz(a, b));
}
#else
static __device__ __forceinline__ unsigned pk16(float a, float b) {
  union { _Float16 h[2]; unsigned u; } x;
  x.h[0] = (_Float16)a; x.h[1] = (_Float16)b; return x.u;
}
#endif

// async global->LDS, 16B per lane; LDS dest must be wave-uniform base (HW adds lane*16)
#define GL2LDS16(g, l) \
  __builtin_amdgcn_global_load_lds((const __attribute__((address_space(1))) unsigned int*)(g), \
      (__attribute__((address_space(3))) unsigned int*)(unsigned int)(uintptr_t)(l), 16, 0, 0)

__global__ void cast_x_kernel(const float* __restrict__ src, _Float16* __restrict__ dst, int n4) {
  int i = blockIdx.x * blockDim.x + threadIdx.x;
  if (i < n4) {
    f4v v = ((const f4v*)src)[i];
    ((h4v*)dst)[i] = __builtin_convertvector(v, h4v);
  }
}

// Stage a 128x32 fp32 tile (rows stride KD) into fp16 LDS [128][32], row-major.
__device__ __forceinline__ void stage_f32_128x32(const float* src, _Float16* dst, int lane, int wav) {
  #pragma unroll
  for (int hh = 0; hh < 2; hh++) {
    int row = hh*64 + wav*16 + (lane >> 2);
    int colf = (lane & 3) * 8;
    const float* p = src + (size_t)row * KD + colf;
    f4v a = *(const f4v*)p;
    f4v b = *(const f4v*)(p + 4);
    h8 v;
    v[0]=(_Float16)a[0]; v[1]=(_Float16)a[1]; v[2]=(_Float16)a[2]; v[3]=(_Float16)a[3];
    v[4]=(_Float16)b[0]; v[5]=(_Float16)b[1]; v[6]=(_Float16)b[2]; v[7]=(_Float16)b[3];
    *(h8*)(dst + row*32 + colf) = v;
  }
}

// ---------------- QKV GEMM: Out[M][N] = A[M][K] * W[N][K]^T + bias, 128x128 tile, BK=32 ----------------
// sel==2 (V) is written TRANSPOSED as Vt[b][h][d][t] so attention needs no LDS transpose.
template<int AMODE>
__global__ __launch_bounds__(256) void gemm_qkv_kernel(
    const _Float16* __restrict__ Xh, const float* __restrict__ Xf,
    const float* __restrict__ Wq, const float* __restrict__ Wk, const float* __restrict__ Wv,
    const float* __restrict__ bq, const float* __restrict__ bk, const float* __restrict__ bv,
    _Float16* __restrict__ Qo, _Float16* __restrict__ Ko, _Float16* __restrict__ Vo)
{
  __shared__ _Float16 As[128*32];
  __shared__ _Float16 Bs[128*32];
  int tid = threadIdx.x;
  int lane = tid & 63, wav = tid >> 6;
  int mb = blockIdx.x;
  int nbg = blockIdx.y;
  int sel = nbg >> 3, nb = nbg & 7;
  const float* W = sel == 0 ? Wq : (sel == 1 ? Wk : Wv);
  const float* bias = sel == 0 ? bq : (sel == 1 ? bk : bv);
  _Float16* Out = sel == 0 ? Qo : (sel == 1 ? Ko : Vo);
  int m0 = mb * 128, n0 = nb * 128;

  f32x4 acc[4][4] = {};

  int r_in = lane >> 2;          // 0..15 row within 16-row chunk
  int c8   = (lane & 3) * 8;     // k-element offset 0,8,16,24
  int l15 = lane & 15, l4 = lane >> 4;
  int wr = (wav >> 1) * 64, wc = (wav & 1) * 64;

  for (int k0 = 0; k0 < KD; k0 += 32) {
    if (AMODE == 0) {
      GL2LDS16(Xh + (size_t)(m0 +      wav*16 + r_in)*KD + k0 + c8, As +        wav*512);
      GL2LDS16(Xh + (size_t)(m0 + 64 + wav*16 + r_in)*KD + k0 + c8, As + 2048 + wav*512);
    } else {
      stage_f32_128x32(Xf + (size_t)m0 * KD + k0, As, lane, wav);
    }
    stage_f32_128x32(W + (size_t)n0 * KD + k0, Bs, lane, wav);
    __syncthreads();

    h8 af[4], bf[4];
    #pragma unroll
    for (int f = 0; f < 4; f++) {
      af[f] = *(const h8*)(As + (wr + f*16 + l15)*32 + l4*8);
      bf[f] = *(const h8*)(Bs + (wc + f*16 + l15)*32 + l4*8);
    }
    #pragma unroll
    for (int i = 0; i < 4; i++)
      #pragma unroll
      for (int j = 0; j < 4; j++)
        acc[i][j] = MFMA16(af[i], bf[j], acc[i][j]);
    __syncthreads();
  }

  if (sel == 2) {
    // transposed V epilogue: Vt[((b*NH+h)*HD+d)*T_ + t], 4 consecutive t per reg quad
    #pragma unroll
    for (int i = 0; i < 4; i++) {
      int mrow = m0 + wr + i*16 + l4*4;
      int bb = mrow >> 11, t = mrow & 2047;
      #pragma unroll
      for (int j = 0; j < 4; j++) {
        int ncol = n0 + wc + j*16 + l15;
        float bval = bias[ncol];
        int hh = ncol >> 6, d = ncol & 63;
        h4v v;
        #pragma unroll
        for (int r = 0; r < 4; r++) v[r] = (_Float16)(acc[i][j][r] + bval);
        *(h4v*)(Vo + ((size_t)(bb*NH + hh)*HD + d)*T_ + t) = v;
      }
    }
  } else {
    #pragma unroll
    for (int i = 0; i < 4; i++) {
      int mrow = m0 + wr + i*16 + l4*4;
      #pragma unroll
      for (int j = 0; j < 4; j++) {
        int ncol = n0 + wc + j*16 + l15;
        float bval = bias[ncol];
        #pragma unroll
        for (int r = 0; r < 4; r++)
          Out[(size_t)(mrow + r)*C_ + ncol] = (_Float16)(acc[i][j][r] + bval);
      }
    }
  }
}

// ---------------- Output projection: Out[M][N] = A[M][K](fp16) * W[N][K]^T(fp32) + bias, clamp ±10 ----------------
__global__ __launch_bounds__(256) void gemm_proj_kernel(
    const _Float16* __restrict__ A, const float* __restrict__ W,
    const float* __restrict__ bias, float* __restrict__ Out)
{
  __shared__ _Float16 As[128*32];
  __shared__ _Float16 Bs[128*32];
  int tid = threadIdx.x;
  int lane = tid & 63, wav = tid >> 6;
  int m0 = blockIdx.x * 128, n0 = blockIdx.y * 128;

  f32x4 acc[4][4] = {};
  int r_in = lane >> 2;
  int c8   = (lane & 3) * 8;
  int l15 = lane & 15, l4 = lane >> 4;
  int wr = (wav >> 1) * 64, wc = (wav & 1) * 64;

  for (int k0 = 0; k0 < KD; k0 += 32) {
    GL2LDS16(A + (size_t)(m0 +      wav*16 + r_in)*KD + k0 + c8, As +        wav*512);
    GL2LDS16(A + (size_t)(m0 + 64 + wav*16 + r_in)*KD + k0 + c8, As + 2048 + wav*512);
    stage_f32_128x32(W + (size_t)n0 * KD + k0, Bs, lane, wav);
    __syncthreads();

    h8 af[4], bf[4];
    #pragma unroll
    for (int f = 0; f < 4; f++) {
      af[f] = *(const h8*)(As + (wr + f*16 + l15)*32 + l4*8);
      bf[f] = *(const h8*)(Bs + (wc + f*16 + l15)*32 + l4*8);
    }
    #pragma unroll
    for (int i = 0; i < 4; i++)
      #pragma unroll
      for (int j = 0; j < 4; j++)
        acc[i][j] = MFMA16(af[i], bf[j], acc[i][j]);
    __syncthreads();
  }

  #pragma unroll
  for (int i = 0; i < 4; i++) {
    int mrow = m0 + wr + i*16 + l4*4;
    #pragma unroll
    for (int j = 0; j < 4; j++) {
      int ncol = n0 + wc + j*16 + l15;
      float bval = bias[ncol];
      #pragma unroll
      for (int r = 0; r < 4; r++) {
        float v = acc[i][j][r] + bval;
        v = fminf(10.f, fmaxf(-10.f, v));
        Out[(size_t)(mrow + r)*C_ + ncol] = v;
      }
    }
  }
}

// ---------------- Flash attention, causal, KV-split, KVBLK=64. ----------------
// Block = 128 threads = 2 waves on ONE 32-row q tile; wave0 takes KV blocks [0,ceil(a/2)),
// wave1 takes [ceil(a/2), a). Each keeps partial (m, l, acc) in the log2 domain;
// wave1 posts partials to LDS, one barrier, wave0 merges (flash-merge: w_i = 2^(m_i-m*))
// and stores. 4096 blocks, longest tile first.
// __launch_bounds__(128) ONLY -- R7's (128,4) forced VGPR=64 and caused 1.5 GB/launch of
// scratch spill traffic (WRITE_SIZE 872 MB). Compiler picks ~128 VGPR -> 16 waves/CU, no spill.
// Swapped QK^T (S^T = K*Q^T) keeps q lane-local; Q pre-scaled by (1/8)*log2(e);
// defer-max (THR=8, log2 units); V pre-transposed in global (Vt[b][h][d][t]);
// O overwrites Q in place (each block's rows x head-slice are exclusively its own).
__global__ __launch_bounds__(128) void attn_kernel(
    const _Float16* Q, const _Float16* __restrict__ K,
    const _Float16* __restrict__ Vt, _Float16* O)
{
  __shared__ _Float16 Plds[2][2][16*72];   // [wave][chain] P[16 q][64 k], row stride 72
  __shared__ float MrgAcc[2][16][64];      // [chain][q row][d col] wave1 partial O
  __shared__ float MrgML[2][2][16];        // [chain][{m,l}][q row]
  int lane = threadIdx.x & 63;
  int w = threadIdx.x >> 6;                // 0 or 1
  int p = blockIdx.x;                      // 4096 blocks
  int t = 63 - (p >> 6);                   // tile, longest first
  int bh = p & 63;
  int b = bh >> 4, h = bh & 15;
  int l15 = lane & 15, l4 = lane >> 4;
  _Float16* PlA = &Plds[w][0][0];
  _Float16* PlB = &Plds[w][1][0];
  const _Float16* Kbh = K + (size_t)b*T_*C_ + h*HD;
  const _Float16* Vbh = Vt + (size_t)(b*NH + h)*HD*T_;
  const _Float16 QSC = (_Float16)0.18033688011f;   // (1/8)*log2(e)

  int q0 = t * 32;
  int qa = q0 + l15, qb = q0 + 16 + l15;
  int a  = (t >> 1) + 1;                   // total 64-key blocks for this tile
  int h0 = (a + 1) >> 1;
  int ibs = w ? h0 : 0;
  int ibe = w ? a : h0;
  int lastb = (a - 1) * 64;                // the (only) masked key block

  const _Float16* qp0 = Q + (size_t)(b*T_ + qa)*C_ + h*HD;
  const _Float16* qp1 = Q + (size_t)(b*T_ + qb)*C_ + h*HD;
  h8 qf00 = *(const h8*)(qp0 + l4*8)      * QSC;
  h8 qf01 = *(const h8*)(qp0 + 32 + l4*8) * QSC;
  h8 qf10 = *(const h8*)(qp1 + l4*8)      * QSC;
  h8 qf11 = *(const h8*)(qp1 + 32 + l4*8) * QSC;

  f32x4 accA[4] = {}, accB[4] = {};
  float mA = -INFINITY, lAp = 0.f;
  float mB = -INFINITY, lBp = 0.f;

#define CHAIN(sv, qrow, m, lp, acc, Pl)                                        \
  {                                                                            \
    float sc[16];                                                              \
    _Pragma("unroll") for (int g = 0; g < 4; g++) {                            \
      sc[g*4+0] = sv[g][0]; sc[g*4+1] = sv[g][1];                              \
      sc[g*4+2] = sv[g][2]; sc[g*4+3] = sv[g][3];                              \
    }                                                                          \
    if (kb == lastb) {                                                         \
      _Pragma("unroll") for (int g = 0; g < 4; g++)                            \
        _Pragma("unroll") for (int r = 0; r < 4; r++)                          \
          if (kb + g*16 + l4*4 + r > (qrow)) sc[g*4+r] = -INFINITY;            \
    }                                                                          \
    float mx = sc[0];                                                          \
    _Pragma("unroll") for (int j = 1; j < 16; j++) mx = fmaxf(mx, sc[j]);      \
    mx = fmaxf(mx, __shfl_xor(mx, 16));                                        \
    mx = fmaxf(mx, __shfl_xor(mx, 32));                                        \
    if (__any(mx > (m) + 8.f)) {                                               \
      float mn = fmaxf((m), mx);                                               \
      float al = EXP2((m) - mn);                                               \
      (lp) *= al;                                                              \
      float av0 = __shfl(al, l4*4+0), av1 = __shfl(al, l4*4+1);                \
      float av2 = __shfl(al, l4*4+2), av3 = __shfl(al, l4*4+3);                \
      _Pragma("unroll") for (int c2 = 0; c2 < 4; c2++) {                       \
        acc[c2][0] *= av0; acc[c2][1] *= av1;                                  \
        acc[c2][2] *= av2; acc[c2][3] *= av3;                                  \
      }                                                                        \
      (m) = mn;                                                                \
    }                                                                          \
    _Pragma("unroll") for (int g = 0; g < 4; g++) {                            \
      float e0 = EXP2(sc[g*4+0] - (m)), e1 = EXP2(sc[g*4+1] - (m));            \
      float e2 = EXP2(sc[g*4+2] - (m)), e3 = EXP2(sc[g*4+3] - (m));            \
      (lp) += (e0 + e1) + (e2 + e3);                                           \
      uint2 u; u.x = pk16(e0, e1); u.y = pk16(e2, e3);                         \
      *(uint2*)((Pl) + l15*72 + g*16 + l4*4) = u;                              \
    }                                                                          \
  }

  h8 kf0, kf1, kf2, kf3, kf4, kf5, kf6, kf7;
  {
    const _Float16* k0p = Kbh + (size_t)(ibs * 64) * C_;
    kf0 = *(const h8*)(k0p + (size_t)(     l15)*C_ + l4*8);
    kf1 = *(const h8*)(k0p + (size_t)(     l15)*C_ + 32 + l4*8);
    kf2 = *(const h8*)(k0p + (size_t)(16 + l15)*C_ + l4*8);
    kf3 = *(const h8*)(k0p + (size_t)(16 + l15)*C_ + 32 + l4*8);
    kf4 = *(const h8*)(k0p + (size_t)(32 + l15)*C_ + l4*8);
    kf5 = *(const h8*)(k0p + (size_t)(32 + l15)*C_ + 32 + l4*8);
    kf6 = *(const h8*)(k0p + (size_t)(48 + l15)*C_ + l4*8);
    kf7 = *(const h8*)(k0p + (size_t)(48 + l15)*C_ + 32 + l4*8);
  }

  #pragma unroll 1
  for (int ib = ibs; ib < ibe; ib++) {
    int kb = ib << 6;
    // V^T fragments (consumed at iteration end -> latency hidden under softmax)
    h8 vf00 = *(const h8*)(Vbh + (size_t)(     l15)*T_ + kb + l4*8);
    h8 vf01 = *(const h8*)(Vbh + (size_t)(     l15)*T_ + kb + 32 + l4*8);
    h8 vf10 = *(const h8*)(Vbh + (size_t)(16 + l15)*T_ + kb + l4*8);
    h8 vf11 = *(const h8*)(Vbh + (size_t)(16 + l15)*T_ + kb + 32 + l4*8);
    h8 vf20 = *(const h8*)(Vbh + (size_t)(32 + l15)*T_ + kb + l4*8);
    h8 vf21 = *(const h8*)(Vbh + (size_t)(32 + l15)*T_ + kb + 32 + l4*8);
    h8 vf30 = *(const h8*)(Vbh + (size_t)(48 + l15)*T_ + kb + l4*8);
    h8 vf31 = *(const h8*)(Vbh + (size_t)(48 + l15)*T_ + kb + 32 + l4*8);

    f32x4 z = {};
    f32x4 sA[4], sB[4];
    sA[0] = MFMA16(kf1, qf01, MFMA16(kf0, qf00, z));
    sA[1] = MFMA16(kf3, qf01, MFMA16(kf2, qf00, z));
    sA[2] = MFMA16(kf5, qf01, MFMA16(kf4, qf00, z));
    sA[3] = MFMA16(kf7, qf01, MFMA16(kf6, qf00, z));
    sB[0] = MFMA16(kf1, qf11, MFMA16(kf0, qf10, z));
    sB[1] = MFMA16(kf3, qf11, MFMA16(kf2, qf10, z));
    sB[2] = MFMA16(kf5, qf11, MFMA16(kf4, qf10, z));
    sB[3] = MFMA16(kf7, qf11, MFMA16(kf6, qf10, z));

    if (ib + 1 < ibe) {      // register-prefetch next K tile
      const _Float16* kn = Kbh + (size_t)(kb + 64)*C_;
      kf0 = *(const h8*)(kn + (size_t)(     l15)*C_ + l4*8);
      kf1 = *(const h8*)(kn + (size_t)(     l15)*C_ + 32 + l4*8);
      kf2 = *(const h8*)(kn + (size_t)(16 + l15)*C_ + l4*8);
      kf3 = *(const h8*)(kn + (size_t)(16 + l15)*C_ + 32 + l4*8);
      kf4 = *(const h8*)(kn + (size_t)(32 + l15)*C_ + l4*8);
      kf5 = *(const h8*)(kn + (size_t)(32 + l15)*C_ + 32 + l4*8);
      kf6 = *(const h8*)(kn + (size_t)(48 + l15)*C_ + l4*8);
      kf7 = *(const h8*)(kn + (size_t)(48 + l15)*C_ + 32 + l4*8);
    }

    CHAIN(sA, qa, mA, lAp, accA, PlA)
    CHAIN(sB, qb, mB, lBp, accB, PlB)

    h8 paA0 = *(const h8*)(PlA + l15*72 + l4*8);
    h8 paA1 = *(const h8*)(PlA + l15*72 + 32 + l4*8);
    h8 paB0 = *(const h8*)(PlB + l15*72 + l4*8);
    h8 paB1 = *(const h8*)(PlB + l15*72 + 32 + l4*8);
    accA[0] = MFMA16(paA1, vf01, MFMA16(paA0, vf00, accA[0]));
    accA[1] = MFMA16(paA1, vf11, MFMA16(paA0, vf10, accA[1]));
    accA[2] = MFMA16(paA1, vf21, MFMA16(paA0, vf20, accA[2]));
    accA[3] = MFMA16(paA1, vf31, MFMA16(paA0, vf30, accA[3]));
    accB[0] = MFMA16(paB1, vf01, MFMA16(paB0, vf00, accB[0]));
    accB[1] = MFMA16(paB1, vf11, MFMA16(paB0, vf10, accB[1]));
    accB[2] = MFMA16(paB1, vf21, MFMA16(paB0, vf20, accB[2]));
    accB[3] = MFMA16(paB1, vf31, MFMA16(paB0, vf30, accB[3]));
  }
#undef CHAIN

  // full row-sum reduce of this wave's l partials
  lAp += __shfl_xor(lAp, 16); lAp += __shfl_xor(lAp, 32);
  lBp += __shfl_xor(lBp, 16); lBp += __shfl_xor(lBp, 32);

  if (w == 1) {
    if (l4 == 0) {
      MrgML[0][0][l15] = mA; MrgML[0][1][l15] = lAp;
      MrgML[1][0][l15] = mB; MrgML[1][1][l15] = lBp;
    }
    #pragma unroll
    for (int c2 = 0; c2 < 4; c2++)
      #pragma unroll
      for (int r = 0; r < 4; r++) {
        MrgAcc[0][l4*4 + r][c2*16 + l15] = accA[c2][r];
        MrgAcc[1][l4*4 + r][c2*16 + l15] = accB[c2][r];
      }
  }
  __syncthreads();
  if (w == 0) {
    #pragma unroll
    for (int r = 0; r < 4; r++) {
      int row = l4*4 + r;
      float m0a = __shfl(mA, row), l0a = __shfl(lAp, row);
      float m0b = __shfl(mB, row), l0b = __shfl(lBp, row);
      float m1a = MrgML[0][0][row], l1a = MrgML[0][1][row];
      float m1b = MrgML[1][0][row], l1b = MrgML[1][1][row];
      float msa = fmaxf(m0a, m1a), msb = fmaxf(m0b, m1b);
      float w0a = EXP2(m0a - msa), w1a = EXP2(m1a - msa);
      float w0b = EXP2(m0b - msb), w1b = EXP2(m1b - msb);
      float ra = 1.f / (w0a*l0a + w1a*l1a);
      float rb = 1.f / (w0b*l0b + w1b*l1b);
      float s0a = w0a*ra, s1a = w1a*ra;
      float s0b = w0b*rb, s1b = w1b*rb;
      #pragma unroll
      for (int c2 = 0; c2 < 4; c2++) {
        float va = accA[c2][r]*s0a + MrgAcc[0][row][c2*16 + l15]*s1a;
        float vb = accB[c2][r]*s0b + MrgAcc[1][row][c2*16 + l15]*s1b;
        va = fminf(10.f, fmaxf(-10.f, va));
        vb = fminf(10.f, fmaxf(-10.f, vb));
        O[(size_t)(b*T_ + q0      + row)*C_ + h*HD + c2*16 + l15] = (_Float16)va;
        O[(size_t)(b*T_ + q0 + 16 + row)*C_ + h*HD + c2*16 + l15] = (_Float16)vb;
      }
    }
  }
}

extern "C" void kernel_launch(void* const* d_in, const int* in_sizes, int n_in,
                              void* d_out, int out_size, void* d_ws, size_t ws_size,
                              hipStream_t stream) {
  (void)in_sizes; (void)n_in; (void)out_size;
  const float* x  = (const float*)d_in[0];
  const float* wq = (const float*)d_in[1];
  const float* bq = (const float*)d_in[2];
  const float* wk = (const float*)d_in[3];
  const float* bk = (const float*)d_in[4];
  const float* wv = (const float*)d_in[5];
  const float* bv = (const float*)d_in[6];
  const float* wp = (const float*)d_in[7];
  const float* bp = (const float*)d_in[8];
  float* out = (float*)d_out;

  char* ws = (char*)d_ws;
  const size_t MB = 1ull << 20;
  _Float16* qh = (_Float16*)(ws + 0*MB);    // 16 MB; attention output written in place
  _Float16* kh = (_Float16*)(ws + 16*MB);   // 16 MB
  _Float16* vh = (_Float16*)(ws + 32*MB);   // 16 MB, TRANSPOSED layout [b][h][d][t]
  _Float16* xh = (_Float16*)(ws + 48*MB);   // 16 MB (only if ws_size >= 64 MB)

  bool use_xh = ws_size >= 64*MB;
  if (use_xh) {
    cast_x_kernel<<<dim3((M_*C_/4) / 256), 256, 0, stream>>>(x, xh, M_*C_/4);
    gemm_qkv_kernel<0><<<dim3(M_/128, 24), 256, 0, stream>>>(
        xh, nullptr, wq, wk, wv, bq, bk, bv, qh, kh, vh);
  } else {
    gemm_qkv_kernel<1><<<dim3(M_/128, 24), 256, 0, stream>>>(
        nullptr, x, wq, wk, wv, bq, bk, bv, qh, kh, vh);
  }
  attn_kernel<<<dim3(4096), 128, 0, stream>>>(qh, kh, vh, qh);
  gemm_proj_kernel<<<dim3(M_/128, C_/128), 256, 0, stream>>>(qh, wp, bp, out);
}